// Round 3
// baseline (2346.548 us; speedup 1.0000x reference)
//
#include <hip/hip_runtime.h>
#include <hip/hip_bf16.h>
#include <math.h>

enum { ACT_NONE = 0, ACT_RELU = 1, ACT_SIG = 2, ACT_TANH_MUL = 3 };

// Generic conv-as-GEMM:  C[b,t,n] = act( sum_k A[b, t*Cin + koff(k)] * W[k,n] + bias[n] )
// koff(k) = k + (k>=Cin ? koffDelta : 0)  -- handles taps=2 dilated convs and 1x1 (K=Cin).
// All tensors fp32. ACT_TANH_MUL: C = tanh(acc+bias) * side[b,t,n].
template<int TM, int TN, int ACT>
__global__ __launch_bounds__(256) void conv_gemm(
    const float* __restrict__ A, long A_bstride,
    const float* __restrict__ W, const float* __restrict__ bias,
    const float* __restrict__ side,
    float* __restrict__ C,
    int L_out, int Cin, int K, int koffDelta, int N)
{
    static_assert(TM == 4, "float4 A-read assumes TM==4");
    constexpr int BM = 16 * TM;   // 64 rows
    constexpr int BN = 16 * TN;   // 64 or 32 cols
    constexpr int BK = 16;

    // k-major A tile; row stride BM+4 floats = 272B (multiple of 16B -> aligned b128 reads)
    __shared__ float As[BK][BM + 4];
    __shared__ float Ws[BK][BN];

    const int tid = threadIdx.x;
    const int tx = tid & 15;
    const int ty = tid >> 4;
    const int m0 = blockIdx.x * BM;
    const int n0 = blockIdx.y * BN;
    const int b  = blockIdx.z;

    const float* Ab = A + (long)b * A_bstride;
    float* Cb = C + (long)b * L_out * N;

    float acc[TM][TN];
#pragma unroll
    for (int i = 0; i < TM; ++i)
#pragma unroll
        for (int j = 0; j < TN; ++j) acc[i][j] = 0.f;

    for (int k0 = 0; k0 < K; k0 += BK) {
        __syncthreads();  // protect previous iteration's LDS reads
        // stage A tile (BM*BK elems, k fastest for coalescing)
#pragma unroll
        for (int idx = tid; idx < BM * BK; idx += 256) {
            int r = idx >> 4;        // row within tile (t)
            int c = idx & 15;        // k within chunk
            int t = m0 + r;
            int k = k0 + c;
            float v = 0.f;
            if (t < L_out && k < K) {
                int o = k + (k >= Cin ? koffDelta : 0);
                v = Ab[(long)t * Cin + o];
            }
            As[c][r] = v;
        }
        // stage W tile
#pragma unroll
        for (int idx = tid; idx < BK * BN; idx += 256) {
            int r = idx / BN;
            int c = idx % BN;
            int k = k0 + r;
            int n = n0 + c;
            Ws[r][c] = (k < K && n < N) ? W[(long)k * N + n] : 0.f;
        }
        __syncthreads();

#pragma unroll
        for (int kk = 0; kk < BK; ++kk) {
            float a[TM];
            float4 av = *(const float4*)&As[kk][ty * TM];
            a[0] = av.x; a[1] = av.y; a[2] = av.z; a[3] = av.w;
            float w[TN];
            if constexpr (TN == 4) {
                float4 wv = *(const float4*)&Ws[kk][tx * TN];
                w[0] = wv.x; w[1] = wv.y; w[2] = wv.z; w[3] = wv.w;
            } else {
                float2 wv = *(const float2*)&Ws[kk][tx * TN];
                w[0] = wv.x; w[1] = wv.y;
            }
#pragma unroll
            for (int i = 0; i < TM; ++i)
#pragma unroll
                for (int j = 0; j < TN; ++j) acc[i][j] += a[i] * w[j];
        }
    }

    // epilogue
#pragma unroll
    for (int i = 0; i < TM; ++i) {
        int t = m0 + ty * TM + i;
        if (t >= L_out) continue;
#pragma unroll
        for (int j = 0; j < TN; ++j) {
            int n = n0 + tx * TN + j;
            if (n >= N) continue;
            float v = acc[i][j] + bias[n];
            if constexpr (ACT == ACT_RELU)     v = fmaxf(v, 0.f);
            else if constexpr (ACT == ACT_SIG) v = 1.f / (1.f + expf(-v));
            else if constexpr (ACT == ACT_TANH_MUL)
                v = tanhf(v) * side[((long)b * L_out + t) * N + n];
            Cb[(long)t * N + n] = v;
        }
    }
}

// Z[b,t,c] = prev[b, t+off, c] + cur[b,t,c]   (24 channels)
__global__ __launch_bounds__(256) void add_trim(
    const float* __restrict__ prev, const float* __restrict__ cur,
    float* __restrict__ Z, int Lp, int Lc, int off)
{
    long total = (long)8 * Lc * 24;
    long stride = (long)gridDim.x * blockDim.x;
    long per = (long)Lc * 24;
    for (long i = (long)blockIdx.x * blockDim.x + threadIdx.x; i < total; i += stride) {
        int b = (int)(i / per);
        long rem = i - (long)b * per;
        int t = (int)(rem / 24);
        int c = (int)(rem - (long)t * 24);
        Z[i] = prev[((long)b * Lp + t + off) * 24 + c] + cur[i];
    }
}

// Fused final 1x1 conv 256->256 + softmax over channels. Block: 8 rows of 256 ch.
// OUTPUT IS FP32 (harness reads fp32; round-2 evidence).
__global__ __launch_bounds__(256) void f2_softmax(
    const float* __restrict__ A, const float* __restrict__ W,
    const float* __restrict__ bias, float* __restrict__ out, int L)
{
    __shared__ float As[8][256];
    __shared__ float Ws[32][256];
    const int tid = threadIdx.x;
    const int b = blockIdx.y;
    const int t0 = blockIdx.x * 8;
    const float* Ab = A + ((long)b * L + t0) * 256;

#pragma unroll
    for (int r = 0; r < 8; ++r) As[r][tid] = Ab[(long)r * 256 + tid];

    const int tx = tid & 63;
    const int ty = tid >> 6;
    float acc[2][4] = {{0.f,0.f,0.f,0.f},{0.f,0.f,0.f,0.f}};

    for (int c = 0; c < 256; c += 32) {
        __syncthreads();
#pragma unroll
        for (int r = 0; r < 32; ++r) Ws[r][tid] = W[(long)(c + r) * 256 + tid];
        __syncthreads();
#pragma unroll
        for (int kk = 0; kk < 32; kk += 4) {
            float4 a0 = *(const float4*)&As[ty * 2 + 0][c + kk];
            float4 a1 = *(const float4*)&As[ty * 2 + 1][c + kk];
            float a0v[4] = {a0.x, a0.y, a0.z, a0.w};
            float a1v[4] = {a1.x, a1.y, a1.z, a1.w};
#pragma unroll
            for (int q = 0; q < 4; ++q) {
                float4 wq = *(const float4*)&Ws[kk + q][tx * 4];
                float wv[4] = {wq.x, wq.y, wq.z, wq.w};
#pragma unroll
                for (int j = 0; j < 4; ++j) {
                    acc[0][j] += a0v[q] * wv[j];
                    acc[1][j] += a1v[q] * wv[j];
                }
            }
        }
    }

    __syncthreads();  // done reading As in k-loop
#pragma unroll
    for (int j = 0; j < 4; ++j) {
        float bv = bias[tx * 4 + j];
        As[ty * 2 + 0][tx * 4 + j] = acc[0][j] + bv;
        As[ty * 2 + 1][tx * 4 + j] = acc[1][j] + bv;
    }
    __syncthreads();

    // softmax: wave w handles rows 2w, 2w+1
    const int wave = tid >> 6;
    const int lane = tid & 63;
#pragma unroll
    for (int rr = 0; rr < 2; ++rr) {
        int t = wave * 2 + rr;
        float v[4];
#pragma unroll
        for (int q = 0; q < 4; ++q) v[q] = As[t][lane + 64 * q];
        float m = fmaxf(fmaxf(v[0], v[1]), fmaxf(v[2], v[3]));
        for (int off = 32; off > 0; off >>= 1) m = fmaxf(m, __shfl_xor(m, off));
        float e[4], s = 0.f;
#pragma unroll
        for (int q = 0; q < 4; ++q) { e[q] = expf(v[q] - m); s += e[q]; }
        for (int off = 32; off > 0; off >>= 1) s += __shfl_xor(s, off);
        float inv = 1.f / s;
        float* ob = out + ((long)b * L + t0 + t) * 256;
#pragma unroll
        for (int q = 0; q < 4; ++q) ob[lane + 64 * q] = e[q] * inv;
    }
}

extern "C" void kernel_launch(void* const* d_in, const int* in_sizes, int n_in,
                              void* d_out, int out_size, void* d_ws, size_t ws_size,
                              hipStream_t stream)
{
    // ALL inputs fp32 (round-1 NaN proves bf16 read is wrong); output fp32
    // (round-2 exact-2^-8 error proves bf16 write covers only half the buffer).
    const float* x        = (const float*)d_in[0];
    const float* causal_W = (const float*)d_in[1];
    const float* causal_b = (const float*)d_in[2];
    const float* gW0      = (const float*)d_in[3];
    const float* gb0      = (const float*)d_in[4];
    const float* fW0      = (const float*)d_in[5];
    const float* fb0      = (const float*)d_in[6];
    const float* sW0      = (const float*)d_in[7];
    const float* sb0      = (const float*)d_in[8];
    const float* gate_W   = (const float*)d_in[9];
    const float* gate_b   = (const float*)d_in[10];
    const float* filter_W = (const float*)d_in[11];
    const float* filter_b = (const float*)d_in[12];
    const float* scale_W  = (const float*)d_in[13];
    const float* scale_b  = (const float*)d_in[14];
    const float* res_W    = (const float*)d_in[15];
    const float* res_b    = (const float*)d_in[16];
    const float* f1_W     = (const float*)d_in[17];
    const float* f1_b     = (const float*)d_in[18];
    const float* f2_W     = (const float*)d_in[19];
    const float* f2_b     = (const float*)d_in[20];

    // Workspace layout (fp32 intermediates, ~241 MB total)
    char* w = (char*)d_ws;
    float* Y0  = (float*)w; w += (size_t)8 * 16383 * 256 * 4;  // causal out; later reused as A1
    float* G   = (float*)w; w += (size_t)8 * 16382 * 24 * 4;   // sigmoid gate; later reused as Z
    float* H   = (float*)w; w += (size_t)8 * 16382 * 24 * 4;   // tanh*sig product
    float* P0  = (float*)w; w += (size_t)8 * 16382 * 24 * 4;
    float* P1  = (float*)w; w += (size_t)8 * 16382 * 24 * 4;
    float* ACC = (float*)w;                                     // 8*15360*128*4
    float* A1 = Y0;
    float* Z  = G;

    dim3 blk(256);

    // 1) causal conv: K=2,d=1, 256->256
    {
        int L = 16383;
        dim3 g((L + 63) / 64, 4, 8);
        conv_gemm<4, 4, ACT_NONE><<<g, blk, 0, stream>>>(
            x, (long)16384 * 256, causal_W, causal_b, nullptr, Y0, L, 256, 512, 0, 256);
    }
    // 2) gated block 0: 256->24, K=2, d=1
    {
        int L = 16382;
        dim3 g((L + 63) / 64, 1, 8);
        conv_gemm<4, 2, ACT_SIG><<<g, blk, 0, stream>>>(
            Y0, (long)16383 * 256, gW0, gb0, nullptr, G, L, 256, 512, 0, 24);
        conv_gemm<4, 2, ACT_TANH_MUL><<<g, blk, 0, stream>>>(
            Y0, (long)16383 * 256, fW0, fb0, G, H, L, 256, 512, 0, 24);
        conv_gemm<4, 2, ACT_NONE><<<g, blk, 0, stream>>>(
            H, (long)16382 * 24, sW0, sb0, nullptr, P0, L, 24, 24, 0, 24);
    }
    // 3) 9 dilated gated blocks, 24->24
    float* Pprev = P0;
    float* Pnext = P1;
    int Lprev = 16382;
    for (int i = 0; i < 9; ++i) {
        int d = 2 << i;            // 2,4,...,512
        int L = Lprev - d;
        dim3 g((L + 63) / 64, 1, 8);
        conv_gemm<4, 2, ACT_SIG><<<g, blk, 0, stream>>>(
            Pprev, (long)Lprev * 24, gate_W + (size_t)i * 1152, gate_b + i * 24,
            nullptr, G, L, 24, 48, 24 * (d - 1), 24);
        conv_gemm<4, 2, ACT_TANH_MUL><<<g, blk, 0, stream>>>(
            Pprev, (long)Lprev * 24, filter_W + (size_t)i * 1152, filter_b + i * 24,
            G, H, L, 24, 48, 24 * (d - 1), 24);
        conv_gemm<4, 2, ACT_NONE><<<g, blk, 0, stream>>>(
            H, (long)L * 24, scale_W + (size_t)i * 576, scale_b + i * 24,
            nullptr, Pnext, L, 24, 24, 0, 24);
        float* tmp = Pprev; Pprev = Pnext; Pnext = tmp;  // Pprev = this layer's out
        Lprev = L;
    }
    // Reference overwrites acc every iteration -> only i=8's res conv survives.
    // 4) Z = trim(layer7_out, 256) + layer8_out
    add_trim<<<dim3(2048), blk, 0, stream>>>(Pnext, Pprev, Z, 15872, 15360, 256);
    // 5) res conv 24->128 + fused relu
    {
        int L = 15360;
        dim3 g((L + 63) / 64, 2, 8);
        conv_gemm<4, 4, ACT_RELU><<<g, blk, 0, stream>>>(
            Z, (long)15360 * 24, res_W + (size_t)8 * 24 * 128, res_b + 8 * 128,
            nullptr, ACC, L, 24, 24, 0, 128);
    }
    // 6) f1: 128->256 + relu
    {
        int L = 15360;
        dim3 g((L + 63) / 64, 4, 8);
        conv_gemm<4, 4, ACT_RELU><<<g, blk, 0, stream>>>(
            ACC, (long)15360 * 128, f1_W, f1_b, nullptr, A1, L, 128, 128, 0, 256);
    }
    // 7) f2 256->256 fused with softmax -> fp32 out
    {
        dim3 g(15360 / 8, 8);
        f2_softmax<<<g, blk, 0, stream>>>(A1, f2_W, f2_b, (float*)d_out, 15360);
    }
}

// Round 4
// 904.670 us; speedup vs baseline: 2.5938x; 2.5938x over previous
//
#include <hip/hip_runtime.h>
#include <math.h>

typedef unsigned short u16;
typedef __attribute__((ext_vector_type(8))) short short8;
typedef __attribute__((ext_vector_type(4))) float f32x4;

#define PBSTR ((long)16382 * 24)

__device__ __forceinline__ u16 f2bf(float f) {
    unsigned u = __float_as_uint(f);
    unsigned r = u + 0x7FFFu + ((u >> 16) & 1u);
    return (u16)(r >> 16);
}
__device__ __forceinline__ unsigned pk2(float a, float b) {
    return (unsigned)f2bf(a) | ((unsigned)f2bf(b) << 16);
}
__device__ __forceinline__ float sigf(float x) { return 1.f / (1.f + __expf(-x)); }
__device__ __forceinline__ float tanhfast(float x) { return 2.f / (1.f + __expf(-2.f * x)) - 1.f; }

// ---------------------------------------------------------------------------
// Prep 1: composite (causal ∘ gate/filter) weights, transposed, bf16.
// Wt[nr][k] (64 x 768), nr<24: gate, 24<=nr<48: filter, 48..63: zero pad.
// k = tau*256 + ci.  Wc[tau][ci][n] = sum_{i+j=tau} sum_o cW[i][ci][o]*G[j][o][n]
__global__ __launch_bounds__(256) void build_gf_w(
    const float* __restrict__ cW, const float* __restrict__ cb,
    const float* __restrict__ gW, const float* __restrict__ gb,
    const float* __restrict__ fW, const float* __restrict__ fb,
    u16* __restrict__ Wt, float* __restrict__ biasGF)
{
    int idx = blockIdx.x * 256 + threadIdx.x;   // 0..49151
    if (idx < 49152) {
        int nr = idx / 768, k = idx % 768, tau = k / 256, ci = k % 256;
        float val = 0.f;
        if (nr < 48) {
            const float* G = (nr < 24) ? gW : fW;
            int n = (nr < 24) ? nr : nr - 24;
            auto dotf = [&](int i, int j) {
                const float* a = cW + i * 65536 + ci * 256;
                const float* g = G + j * 6144 + n;
                float s = 0.f;
                for (int o = 0; o < 256; ++o) s += a[o] * g[o * 24];
                return s;
            };
            if (tau == 0)      val = dotf(0, 0);
            else if (tau == 1) val = dotf(0, 1) + dotf(1, 0);
            else               val = dotf(1, 1);
        }
        Wt[idx] = f2bf(val);
    }
    if (blockIdx.x == 0 && threadIdx.x < 48) {
        int nr = threadIdx.x;
        const float* G = (nr < 24) ? gW : fW;
        const float* B = (nr < 24) ? gb : fb;
        int n = (nr < 24) ? nr : nr - 24;
        float s = B[n];
        for (int o = 0; o < 256; ++o) s += cb[o] * (G[o * 24 + n] + G[6144 + o * 24 + n]);
        biasGF[nr] = s;
    }
}

// Prep 2: transpose+bf16 f1_W [128][256]->Wt1[256][128], f2_W->Wt2[256][256],
// res_W[8] [24][128]->Wtr[128][32] (k padded 24->32 with zeros).
__global__ __launch_bounds__(256) void build_wt_misc(
    const float* __restrict__ f1W, const float* __restrict__ f2W,
    const float* __restrict__ resW8,
    u16* __restrict__ Wt1, u16* __restrict__ Wt2, u16* __restrict__ Wtr)
{
    int idx = blockIdx.x * 256 + threadIdx.x;   // 0..102399
    if (idx < 32768) {
        int n = idx / 128, k = idx % 128;
        Wt1[idx] = f2bf(f1W[k * 256 + n]);
    } else if (idx < 98304) {
        int j = idx - 32768; int n = j / 256, k = j % 256;
        Wt2[j] = f2bf(f2W[k * 256 + n]);
    } else if (idx < 102400) {
        int j = idx - 98304; int n = j / 32, k = j % 32;
        Wtr[j] = (k < 24) ? f2bf(resW8[k * 128 + n]) : (u16)0;
    }
}

// ---------------------------------------------------------------------------
// Generic MFMA GEMM: C[b,t,n] = act( sum_k A[b][t*A_rs+k] * Wt[n][k] + bias[n] )
// A fp32 (converted to bf16 in staging), Wt bf16 [>=n0+64][Ktot].
// BM=64, BN=64, BK=32. 4 waves, each 32x32 via 2x2 mfma_f32_16x16x32_bf16.
template<int ACT>   // 0 none, 1 relu
__global__ __launch_bounds__(256) void mfma_gemm(
    const float* __restrict__ A, long A_bstride, int A_rs,
    const u16* __restrict__ Wt, const float* __restrict__ bias,
    float* __restrict__ C, long C_bstride,
    int L_out, int Kphys, int Ktot, int N)
{
    __shared__ u16 As[64 * 40];   // row t, k contiguous, stride 40 (80B, 16B-aligned)
    __shared__ u16 Bs[64 * 40];   // row n, k contiguous
    const int tid = threadIdx.x;
    const int m0 = blockIdx.x * 64;
    const int n0 = blockIdx.y * 64;
    const int b = blockIdx.z;
    const float* Ab = A + (long)b * A_bstride;

    const int wv = tid >> 6, lane = tid & 63;
    const int wm = wv >> 1, wn = wv & 1;
    const int col = lane & 15, quad = lane >> 4;

    f32x4 acc[2][2];
#pragma unroll
    for (int i = 0; i < 2; ++i)
#pragma unroll
        for (int j = 0; j < 2; ++j) acc[i][j] = (f32x4){0.f, 0.f, 0.f, 0.f};

    const int srow = tid >> 2;        // 0..63
    const int sk = (tid & 3) * 8;     // 0,8,16,24

    for (int k0 = 0; k0 < Ktot; k0 += 32) {
        __syncthreads();
        // stage A (fp32 -> bf16)
        {
            int t = m0 + srow;
            float4 v0 = make_float4(0.f, 0.f, 0.f, 0.f);
            float4 v1 = v0;
            if (t < L_out && (k0 + sk) < Kphys) {
                const float* p = Ab + (long)t * A_rs + k0 + sk;
                v0 = *(const float4*)p;
                v1 = *(const float4*)(p + 4);
            }
            uint4 w;
            w.x = pk2(v0.x, v0.y); w.y = pk2(v0.z, v0.w);
            w.z = pk2(v1.x, v1.y); w.w = pk2(v1.z, v1.w);
            *(uint4*)&As[srow * 40 + sk] = w;
        }
        // stage B (already bf16, pre-transposed)
        *(uint4*)&Bs[srow * 40 + sk] =
            *(const uint4*)(Wt + (long)(n0 + srow) * Ktot + k0 + sk);
        __syncthreads();

        short8 a0 = *(const short8*)&As[(wm * 32 + col) * 40 + quad * 8];
        short8 a1 = *(const short8*)&As[(wm * 32 + 16 + col) * 40 + quad * 8];
        short8 b0 = *(const short8*)&Bs[(wn * 32 + col) * 40 + quad * 8];
        short8 b1 = *(const short8*)&Bs[(wn * 32 + 16 + col) * 40 + quad * 8];
        acc[0][0] = __builtin_amdgcn_mfma_f32_16x16x32_bf16(a0, b0, acc[0][0], 0, 0, 0);
        acc[0][1] = __builtin_amdgcn_mfma_f32_16x16x32_bf16(a0, b1, acc[0][1], 0, 0, 0);
        acc[1][0] = __builtin_amdgcn_mfma_f32_16x16x32_bf16(a1, b0, acc[1][0], 0, 0, 0);
        acc[1][1] = __builtin_amdgcn_mfma_f32_16x16x32_bf16(a1, b1, acc[1][1], 0, 0, 0);
    }

#pragma unroll
    for (int mt = 0; mt < 2; ++mt)
#pragma unroll
        for (int nt = 0; nt < 2; ++nt)
#pragma unroll
            for (int r = 0; r < 4; ++r) {
                int t = m0 + wm * 32 + mt * 16 + quad * 4 + r;
                int n = n0 + wn * 32 + nt * 16 + col;
                if (t < L_out) {
                    float v = acc[mt][nt][r] + bias[n];
                    if (ACT == 1) v = fmaxf(v, 0.f);
                    C[(long)b * C_bstride + (long)t * N + n] = v;
                }
            }
}

// ---------------------------------------------------------------------------
// Fused first stage: composite 256->48 K=3 conv (MFMA) -> sigmoid*tanh -> 24x24
// s-conv -> P0.  Replaces causal conv + gate0 + filter0 + mul + sconv0.
__global__ __launch_bounds__(256) void gf_fused(
    const float* __restrict__ x, const u16* __restrict__ Wt,
    const float* __restrict__ biasGF,
    const float* __restrict__ sW, const float* __restrict__ sb,
    float* __restrict__ P)
{
    __shared__ u16 As[64 * 40];
    __shared__ u16 Bs[64 * 40];
    __shared__ float pre[64 * 52];
    __shared__ float hbuf[64 * 28];
    __shared__ float WsT[24 * 28];
    __shared__ float biasL[64];
    __shared__ float sbL[24];
    const int tid = threadIdx.x;
    const int m0 = blockIdx.x * 64;
    const int b = blockIdx.z;
    const float* xb = x + (long)b * (16384 * 256);
    const int L = 16382;

    if (tid < 64) biasL[tid] = (tid < 48) ? biasGF[tid] : 0.f;
    if (tid < 24) sbL[tid] = sb[tid];
    for (int i = tid; i < 576; i += 256) { int c = i / 24, n = i % 24; WsT[n * 28 + c] = sW[i]; }

    const int wv = tid >> 6, lane = tid & 63;
    const int wm = wv >> 1, wn = wv & 1;
    const int col = lane & 15, quad = lane >> 4;

    f32x4 acc[2][2];
#pragma unroll
    for (int i = 0; i < 2; ++i)
#pragma unroll
        for (int j = 0; j < 2; ++j) acc[i][j] = (f32x4){0.f, 0.f, 0.f, 0.f};

    const int srow = tid >> 2;
    const int sk = (tid & 3) * 8;

    for (int k0 = 0; k0 < 768; k0 += 32) {
        __syncthreads();
        {
            int t = m0 + srow;
            float4 v0 = make_float4(0.f, 0.f, 0.f, 0.f);
            float4 v1 = v0;
            if (t < L) {   // x rows t..t+2 flattened: xb[t*256 + k], k<768 stays in-bounds
                const float* p = xb + (long)t * 256 + k0 + sk;
                v0 = *(const float4*)p;
                v1 = *(const float4*)(p + 4);
            }
            uint4 w;
            w.x = pk2(v0.x, v0.y); w.y = pk2(v0.z, v0.w);
            w.z = pk2(v1.x, v1.y); w.w = pk2(v1.z, v1.w);
            *(uint4*)&As[srow * 40 + sk] = w;
        }
        *(uint4*)&Bs[srow * 40 + sk] =
            *(const uint4*)(Wt + (long)srow * 768 + k0 + sk);
        __syncthreads();

        short8 a0 = *(const short8*)&As[(wm * 32 + col) * 40 + quad * 8];
        short8 a1 = *(const short8*)&As[(wm * 32 + 16 + col) * 40 + quad * 8];
        short8 b0 = *(const short8*)&Bs[(wn * 32 + col) * 40 + quad * 8];
        short8 b1 = *(const short8*)&Bs[(wn * 32 + 16 + col) * 40 + quad * 8];
        acc[0][0] = __builtin_amdgcn_mfma_f32_16x16x32_bf16(a0, b0, acc[0][0], 0, 0, 0);
        acc[0][1] = __builtin_amdgcn_mfma_f32_16x16x32_bf16(a0, b1, acc[0][1], 0, 0, 0);
        acc[1][0] = __builtin_amdgcn_mfma_f32_16x16x32_bf16(a1, b0, acc[1][0], 0, 0, 0);
        acc[1][1] = __builtin_amdgcn_mfma_f32_16x16x32_bf16(a1, b1, acc[1][1], 0, 0, 0);
    }

    // preacts -> LDS (cols 0-23 gate, 24-47 filter)
#pragma unroll
    for (int mt = 0; mt < 2; ++mt)
#pragma unroll
        for (int nt = 0; nt < 2; ++nt)
#pragma unroll
            for (int r = 0; r < 4; ++r) {
                int rowl = wm * 32 + mt * 16 + quad * 4 + r;
                int cg = wn * 32 + nt * 16 + col;
                if (cg < 48) pre[rowl * 52 + cg] = acc[mt][nt][r] + biasL[cg];
            }
    __syncthreads();
    for (int i = tid; i < 1536; i += 256) {
        int t = i / 24, c = i % 24;
        hbuf[t * 28 + c] = sigf(pre[t * 52 + c]) * tanhfast(pre[t * 52 + 24 + c]);
    }
    __syncthreads();
    // 24x24 s-conv, write P0
    if (tid < 192) {
        int n = tid % 24, tg = tid / 24;
        float o[8];
#pragma unroll
        for (int tt = 0; tt < 8; ++tt) o[tt] = sbL[n];
#pragma unroll
        for (int q = 0; q < 6; ++q) {
            float4 w = *(const float4*)&WsT[n * 28 + q * 4];
#pragma unroll
            for (int tt = 0; tt < 8; ++tt) {
                float4 hv = *(const float4*)&hbuf[(tg * 8 + tt) * 28 + q * 4];
                o[tt] += hv.x * w.x + hv.y * w.y + hv.z * w.z + hv.w * w.w;
            }
        }
#pragma unroll
        for (int tt = 0; tt < 8; ++tt) {
            int t = m0 + tg * 8 + tt;
            if (t < L) P[(long)b * PBSTR + (long)t * 24 + n] = o[tt];
        }
    }
}

// ---------------------------------------------------------------------------
// Fused dilated gated layer (fp32): Q = sconv( tanh(conv_f) * sig(conv_g) )
// [+ trim-add when trimOff>=0].  64 timesteps per block.
__global__ __launch_bounds__(256) void gated_layer(
    const float* __restrict__ P,
    const float* __restrict__ gW, const float* __restrict__ gb,
    const float* __restrict__ fW, const float* __restrict__ fb,
    const float* __restrict__ sW, const float* __restrict__ sb,
    float* __restrict__ Q, int Lin, int Lout, int d, int trimOff)
{
    __shared__ float WgT[24 * 48];
    __shared__ float WfT[24 * 48];
    __shared__ float WsT[24 * 28];
    __shared__ float sCat[64 * 48];   // cols 0-23: strip t, 24-47: strip t+d
    __shared__ float s2[64 * 28];
    __shared__ float hbuf[64 * 28];
    __shared__ float gbL[24], fbL[24], sbL[24];
    const int tid = threadIdx.x;
    const int m0 = blockIdx.x * 64;
    const int b = blockIdx.z;
    const float* Pb = P + (long)b * PBSTR;

    for (int i = tid; i < 1152; i += 256) {
        int tap = i / 576, r = i % 576, ci = r / 24, n = r % 24;
        WgT[n * 48 + tap * 24 + ci] = gW[i];
        WfT[n * 48 + tap * 24 + ci] = fW[i];
    }
    for (int i = tid; i < 576; i += 256) { int c = i / 24, n = i % 24; WsT[n * 28 + c] = sW[i]; }
    if (tid < 24) { gbL[tid] = gb[tid]; fbL[tid] = fb[tid]; sbL[tid] = sb[tid]; }
    for (int i = tid; i < 1536; i += 256) {
        int t = i / 24, c = i % 24;
        int r0 = m0 + t, r1 = r0 + d;
        sCat[t * 48 + c]      = (r0 < Lin) ? Pb[(long)r0 * 24 + c] : 0.f;
        sCat[t * 48 + 24 + c] = (r1 < Lin) ? Pb[(long)r1 * 24 + c] : 0.f;
        if (trimOff >= 0) {
            int r2 = r0 + trimOff;
            s2[t * 28 + c] = (r2 < Lin) ? Pb[(long)r2 * 24 + c] : 0.f;
        }
    }
    __syncthreads();
    if (tid < 192) {
        int c = tid % 24, tg = tid / 24;
        float ag[8], af[8];
#pragma unroll
        for (int tt = 0; tt < 8; ++tt) { ag[tt] = gbL[c]; af[tt] = fbL[c]; }
#pragma unroll
        for (int q = 0; q < 12; ++q) {
            float4 wg = *(const float4*)&WgT[c * 48 + q * 4];
            float4 wf = *(const float4*)&WfT[c * 48 + q * 4];
#pragma unroll
            for (int tt = 0; tt < 8; ++tt) {
                float4 sv = *(const float4*)&sCat[(tg * 8 + tt) * 48 + q * 4];
                ag[tt] += sv.x * wg.x + sv.y * wg.y + sv.z * wg.z + sv.w * wg.w;
                af[tt] += sv.x * wf.x + sv.y * wf.y + sv.z * wf.z + sv.w * wf.w;
            }
        }
#pragma unroll
        for (int tt = 0; tt < 8; ++tt)
            hbuf[(tg * 8 + tt) * 28 + c] = sigf(ag[tt]) * tanhfast(af[tt]);
    }
    __syncthreads();
    if (tid < 192) {
        int n = tid % 24, tg = tid / 24;
        float o[8];
#pragma unroll
        for (int tt = 0; tt < 8; ++tt) o[tt] = sbL[n];
#pragma unroll
        for (int q = 0; q < 6; ++q) {
            float4 w = *(const float4*)&WsT[n * 28 + q * 4];
#pragma unroll
            for (int tt = 0; tt < 8; ++tt) {
                float4 hv = *(const float4*)&hbuf[(tg * 8 + tt) * 28 + q * 4];
                o[tt] += hv.x * w.x + hv.y * w.y + hv.z * w.z + hv.w * w.w;
            }
        }
#pragma unroll
        for (int tt = 0; tt < 8; ++tt) {
            int t = m0 + tg * 8 + tt;
            if (t < Lout) {
                float v = o[tt];
                if (trimOff >= 0) v += s2[(tg * 8 + tt) * 28 + n];
                Q[(long)b * PBSTR + (long)t * 24 + n] = v;
            }
        }
    }
}

// ---------------------------------------------------------------------------
// Fused f2 (256->256 1x1, MFMA) + softmax.  Block = 64 rows; wave = 16 rows x 256 cols.
__global__ __launch_bounds__(256) void f2_softmax_mfma(
    const float* __restrict__ A, const u16* __restrict__ Wt2,
    const float* __restrict__ bias, float* __restrict__ out)
{
    __shared__ u16 As[64 * 40];
    __shared__ u16 Bs[256 * 40];
    __shared__ float biasL[256];
    const int tid = threadIdx.x;
    const int b = blockIdx.y;
    const int t0 = blockIdx.x * 64;
    const float* Ab = A + ((long)b * 15360 + t0) * 256;
    biasL[tid] = bias[tid];

    const int wv = tid >> 6, lane = tid & 63;
    const int col = lane & 15, quad = lane >> 4;
    f32x4 acc[16];
#pragma unroll
    for (int i = 0; i < 16; ++i) acc[i] = (f32x4){0.f, 0.f, 0.f, 0.f};

    const int srow = tid >> 2;
    const int sk = (tid & 3) * 8;

    for (int k0 = 0; k0 < 256; k0 += 32) {
        __syncthreads();
        {
            const float* p = Ab + (long)srow * 256 + k0 + sk;
            float4 v0 = *(const float4*)p;
            float4 v1 = *(const float4*)(p + 4);
            uint4 w;
            w.x = pk2(v0.x, v0.y); w.y = pk2(v0.z, v0.w);
            w.z = pk2(v1.x, v1.y); w.w = pk2(v1.z, v1.w);
            *(uint4*)&As[srow * 40 + sk] = w;
        }
        {
            const uint4* p = (const uint4*)(Wt2 + (long)tid * 256 + k0);
            *(uint4*)&Bs[tid * 40 + 0]  = p[0];
            *(uint4*)&Bs[tid * 40 + 8]  = p[1];
            *(uint4*)&Bs[tid * 40 + 16] = p[2];
            *(uint4*)&Bs[tid * 40 + 24] = p[3];
        }
        __syncthreads();
        short8 a = *(const short8*)&As[(wv * 16 + col) * 40 + quad * 8];
#pragma unroll
        for (int nt = 0; nt < 16; ++nt) {
            short8 bb = *(const short8*)&Bs[(nt * 16 + col) * 40 + quad * 8];
            acc[nt] = __builtin_amdgcn_mfma_f32_16x16x32_bf16(a, bb, acc[nt], 0, 0, 0);
        }
    }

#pragma unroll
    for (int r = 0; r < 4; ++r) {
        int tl = wv * 16 + quad * 4 + r;
        float v[16];
        float m = -1e30f;
#pragma unroll
        for (int nt = 0; nt < 16; ++nt) {
            v[nt] = acc[nt][r] + biasL[nt * 16 + col];
            m = fmaxf(m, v[nt]);
        }
        m = fmaxf(m, __shfl_xor(m, 1));
        m = fmaxf(m, __shfl_xor(m, 2));
        m = fmaxf(m, __shfl_xor(m, 4));
        m = fmaxf(m, __shfl_xor(m, 8));
        float s = 0.f;
#pragma unroll
        for (int nt = 0; nt < 16; ++nt) { v[nt] = __expf(v[nt] - m); s += v[nt]; }
        s += __shfl_xor(s, 1);
        s += __shfl_xor(s, 2);
        s += __shfl_xor(s, 4);
        s += __shfl_xor(s, 8);
        float inv = 1.f / s;
        float* op = out + ((long)b * 15360 + t0 + tl) * 256;
#pragma unroll
        for (int nt = 0; nt < 16; ++nt) op[nt * 16 + col] = v[nt] * inv;
    }
}

// ---------------------------------------------------------------------------
extern "C" void kernel_launch(void* const* d_in, const int* in_sizes, int n_in,
                              void* d_out, int out_size, void* d_ws, size_t ws_size,
                              hipStream_t stream)
{
    const float* x        = (const float*)d_in[0];
    const float* causal_W = (const float*)d_in[1];
    const float* causal_b = (const float*)d_in[2];
    const float* gW0      = (const float*)d_in[3];
    const float* gb0      = (const float*)d_in[4];
    const float* fW0      = (const float*)d_in[5];
    const float* fb0      = (const float*)d_in[6];
    const float* sW0      = (const float*)d_in[7];
    const float* sb0      = (const float*)d_in[8];
    const float* gate_W   = (const float*)d_in[9];
    const float* gate_b   = (const float*)d_in[10];
    const float* filter_W = (const float*)d_in[11];
    const float* filter_b = (const float*)d_in[12];
    const float* scale_W  = (const float*)d_in[13];
    const float* scale_b  = (const float*)d_in[14];
    const float* res_W    = (const float*)d_in[15];
    const float* res_b    = (const float*)d_in[16];
    const float* f1_W     = (const float*)d_in[17];
    const float* f1_b     = (const float*)d_in[18];
    const float* f2_W     = (const float*)d_in[19];
    const float* f2_b     = (const float*)d_in[20];

    char* w = (char*)d_ws;
    float* ACC = (float*)w; w += (size_t)8 * 15360 * 128 * 4;
    float* A1  = (float*)w; w += (size_t)8 * 15360 * 256 * 4;
    float* P0  = (float*)w; w += (size_t)8 * 16382 * 24 * 4;
    float* P1  = (float*)w; w += (size_t)8 * 16382 * 24 * 4;
    u16* WtGF  = (u16*)w;  w += (size_t)64 * 768 * 2;
    u16* Wt1   = (u16*)w;  w += (size_t)256 * 128 * 2;
    u16* Wt2   = (u16*)w;  w += (size_t)256 * 256 * 2;
    u16* Wtr   = (u16*)w;  w += (size_t)128 * 32 * 2;
    float* biasGF = (float*)w; w += 256;

    dim3 blk(256);

    // prep
    build_gf_w<<<dim3(192), blk, 0, stream>>>(causal_W, causal_b, gW0, gb0, fW0, fb0,
                                              WtGF, biasGF);
    build_wt_misc<<<dim3(400), blk, 0, stream>>>(f1_W, f2_W, res_W + (size_t)8 * 24 * 128,
                                                 Wt1, Wt2, Wtr);

    // fused first stage -> P0  (L = 16382)
    gf_fused<<<dim3(256, 1, 8), blk, 0, stream>>>(x, WtGF, biasGF, sW0, sb0, P0);

    // 9 dilated layers
    float* Pprev = P0;
    float* Pnext = P1;
    int Lprev = 16382;
    for (int i = 0; i < 9; ++i) {
        int d = 2 << i;
        int L = Lprev - d;
        int trim = (i == 8) ? d / 2 : -1;
        gated_layer<<<dim3((L + 63) / 64, 1, 8), blk, 0, stream>>>(
            Pprev, gate_W + (size_t)i * 1152, gate_b + i * 24,
            filter_W + (size_t)i * 1152, filter_b + i * 24,
            scale_W + (size_t)i * 576, scale_b + i * 24,
            Pnext, Lprev, L, d, trim);
        float* tmp = Pprev; Pprev = Pnext; Pnext = tmp;
        Lprev = L;
    }
    // Pprev now holds Z = trim(prev) + out  (L = 15360)

    // res conv 24->128 (K padded to 32) + relu -> ACC
    mfma_gemm<1><<<dim3(240, 2, 8), blk, 0, stream>>>(
        Pprev, PBSTR, 24, Wtr, res_b + 8 * 128, ACC, (long)15360 * 128,
        15360, 24, 32, 128);

    // f1 128->256 + relu -> A1
    mfma_gemm<1><<<dim3(240, 4, 8), blk, 0, stream>>>(
        ACC, (long)15360 * 128, 128, Wt1, f1_b, A1, (long)15360 * 256,
        15360, 128, 128, 256);

    // f2 + softmax -> out
    f2_softmax_mfma<<<dim3(240, 8), blk, 0, stream>>>(A1, Wt2, f2_b, (float*)d_out);
}

// Round 5
// 870.537 us; speedup vs baseline: 2.6955x; 1.0392x over previous
//
#include <hip/hip_runtime.h>
#include <math.h>

typedef unsigned short u16;
typedef __attribute__((ext_vector_type(8))) short short8;
typedef __attribute__((ext_vector_type(4))) float f32x4;

#define PBSTR ((long)16382 * 24)

__device__ __forceinline__ u16 f2bf(float f) {
    unsigned u = __float_as_uint(f);
    unsigned r = u + 0x7FFFu + ((u >> 16) & 1u);
    return (u16)(r >> 16);
}
__device__ __forceinline__ unsigned pk2(float a, float b) {
    return (unsigned)f2bf(a) | ((unsigned)f2bf(b) << 16);
}
__device__ __forceinline__ float sigf(float x) { return 1.f / (1.f + __expf(-x)); }
__device__ __forceinline__ float tanhfast(float x) { return 2.f / (1.f + __expf(-2.f * x)) - 1.f; }

__device__ __forceinline__ short8 ldfrag(const u16* p) { return *(const short8*)p; }
__device__ __forceinline__ short8 ldfrag(const float* p) {
    float4 v0 = *(const float4*)p;
    float4 v1 = *(const float4*)(p + 4);
    union { uint4 u; short8 s; } cv;
    cv.u.x = pk2(v0.x, v0.y); cv.u.y = pk2(v0.z, v0.w);
    cv.u.z = pk2(v1.x, v1.y); cv.u.w = pk2(v1.z, v1.w);
    return cv.s;
}

// ---------------------------------------------------------------------------
__global__ __launch_bounds__(256) void build_gf_w(
    const float* __restrict__ cW, const float* __restrict__ cb,
    const float* __restrict__ gW, const float* __restrict__ gb,
    const float* __restrict__ fW, const float* __restrict__ fb,
    u16* __restrict__ Wt, float* __restrict__ biasGF)
{
    int idx = blockIdx.x * 256 + threadIdx.x;
    if (idx < 49152) {
        int nr = idx / 768, k = idx % 768, tau = k / 256, ci = k % 256;
        float val = 0.f;
        if (nr < 48) {
            const float* G = (nr < 24) ? gW : fW;
            int n = (nr < 24) ? nr : nr - 24;
            auto dotf = [&](int i, int j) {
                const float* a = cW + i * 65536 + ci * 256;
                const float* g = G + j * 6144 + n;
                float s = 0.f;
                for (int o = 0; o < 256; ++o) s += a[o] * g[o * 24];
                return s;
            };
            if (tau == 0)      val = dotf(0, 0);
            else if (tau == 1) val = dotf(0, 1) + dotf(1, 0);
            else               val = dotf(1, 1);
        }
        Wt[idx] = f2bf(val);
    }
    if (blockIdx.x == 0 && threadIdx.x < 48) {
        int nr = threadIdx.x;
        const float* G = (nr < 24) ? gW : fW;
        const float* B = (nr < 24) ? gb : fb;
        int n = (nr < 24) ? nr : nr - 24;
        float s = B[n];
        for (int o = 0; o < 256; ++o) s += cb[o] * (G[o * 24 + n] + G[6144 + o * 24 + n]);
        biasGF[nr] = s;
    }
}

__global__ __launch_bounds__(256) void build_wt_misc(
    const float* __restrict__ f1W, const float* __restrict__ f2W,
    const float* __restrict__ resW8,
    u16* __restrict__ Wt1, u16* __restrict__ Wt2, u16* __restrict__ Wtr)
{
    int idx = blockIdx.x * 256 + threadIdx.x;
    if (idx < 32768) {
        int n = idx / 128, k = idx % 128;
        Wt1[idx] = f2bf(f1W[k * 256 + n]);
    } else if (idx < 98304) {
        int j = idx - 32768; int n = j / 256, k = j % 256;
        Wt2[j] = f2bf(f2W[k * 256 + n]);
    } else if (idx < 102400) {
        int j = idx - 98304; int n = j / 32, k = j % 32;
        Wtr[j] = (k < 24) ? f2bf(resW8[k * 128 + n]) : (u16)0;
    }
}

// ---------------------------------------------------------------------------
template<typename AT, int KTOT, int NTILES, int ACT>
__global__ __launch_bounds__(256) void gemm_bstat(
    const AT* __restrict__ A, long A_bstride, int A_rs,
    const u16* __restrict__ Wt, int Wt_rs,
    const float* __restrict__ bias,
    u16* __restrict__ C, long C_bstride, int C_rs, int L_out)
{
    constexpr int BS = KTOT + 8;
    constexpr int NROWS = NTILES * 16;
    __shared__ __align__(16) u16 Bs[NROWS * BS];
    __shared__ float biasL[NROWS];
    const int tid = threadIdx.x;
    const int n0 = blockIdx.y * NROWS;

    for (int i = tid; i < NROWS * (KTOT / 8); i += 256) {
        int rn = i / (KTOT / 8), kk = i % (KTOT / 8);
        *(uint4*)&Bs[rn * BS + kk * 8] = *(const uint4*)(Wt + (long)(n0 + rn) * Wt_rs + kk * 8);
    }
    if (tid < NROWS) biasL[tid] = bias[n0 + tid];

    const int wv = tid >> 6, lane = tid & 63, col = lane & 15, quad = lane >> 4;
    const int b = blockIdx.z;
    const int m0 = blockIdx.x * 128 + wv * 32;
    const AT* Ab = A + (long)b * A_bstride;
    const int rmax = L_out - 1;

    f32x4 acc[2][NTILES];
#pragma unroll
    for (int i = 0; i < 2; ++i)
#pragma unroll
        for (int j = 0; j < NTILES; ++j) acc[i][j] = (f32x4){0.f, 0.f, 0.f, 0.f};

    __syncthreads();

#pragma unroll
    for (int k0 = 0; k0 < KTOT; k0 += 32) {
        short8 a[2];
#pragma unroll
        for (int mt = 0; mt < 2; ++mt) {
            int r = m0 + mt * 16 + col;
            if (r > rmax) r = rmax;
            a[mt] = ldfrag(Ab + (long)r * A_rs + k0 + quad * 8);
        }
#pragma unroll
        for (int nt = 0; nt < NTILES; ++nt) {
            short8 bb = *(const short8*)&Bs[(nt * 16 + col) * BS + k0 + quad * 8];
            acc[0][nt] = __builtin_amdgcn_mfma_f32_16x16x32_bf16(a[0], bb, acc[0][nt], 0, 0, 0);
            acc[1][nt] = __builtin_amdgcn_mfma_f32_16x16x32_bf16(a[1], bb, acc[1][nt], 0, 0, 0);
        }
    }

#pragma unroll
    for (int mt = 0; mt < 2; ++mt)
#pragma unroll
        for (int nt = 0; nt < NTILES; ++nt)
#pragma unroll
            for (int rr = 0; rr < 4; ++rr) {
                int t = m0 + mt * 16 + quad * 4 + rr;
                if (t < L_out) {
                    float v = acc[mt][nt][rr] + biasL[nt * 16 + col];
                    if (ACT == 1) v = fmaxf(v, 0.f);
                    C[(long)b * C_bstride + (long)t * C_rs + n0 + nt * 16 + col] = f2bf(v);
                }
            }
}

// ---------------------------------------------------------------------------
__global__ __launch_bounds__(256) void gf_fused_v2(
    const float* __restrict__ x, const u16* __restrict__ Wt,
    const float* __restrict__ biasGF,
    const float* __restrict__ sW, const float* __restrict__ sb,
    float* __restrict__ P)
{
    __shared__ __align__(16) union {
        u16 bs[48 * 776];
        struct { float pre[128 * 52]; float h[128 * 28]; } ep;
    } U;
    __shared__ float WsT[24 * 28];
    __shared__ float biasL[48];
    __shared__ float sbL[24];

    const int tid = threadIdx.x;
    const int m0 = blockIdx.x * 128;
    const int b = blockIdx.z;
    const float* xb = x + (long)b * (16384 * 256);
    const int L = 16382;

    for (int i = tid; i < 4608; i += 256) {
        int rn = i / 96, kk = i % 96;
        *(uint4*)&U.bs[rn * 776 + kk * 8] = *(const uint4*)(Wt + (long)rn * 768 + kk * 8);
    }
    for (int i = tid; i < 576; i += 256) { int c = i / 24, n = i % 24; WsT[n * 28 + c] = sW[i]; }
    if (tid < 48) biasL[tid] = biasGF[tid];
    if (tid < 24) sbL[tid] = sb[tid];

    const int wv = tid >> 6, lane = tid & 63, col = lane & 15, quad = lane >> 4;

    f32x4 acc[2][3];
#pragma unroll
    for (int i = 0; i < 2; ++i)
#pragma unroll
        for (int j = 0; j < 3; ++j) acc[i][j] = (f32x4){0.f, 0.f, 0.f, 0.f};

    __syncthreads();

    for (int k0 = 0; k0 < 768; k0 += 32) {
        short8 a[2];
#pragma unroll
        for (int mt = 0; mt < 2; ++mt) {
            int g = m0 + wv * 32 + mt * 16 + col;
            if (g > 16381) g = 16381;
            a[mt] = ldfrag(xb + (long)g * 256 + k0 + quad * 8);
        }
#pragma unroll
        for (int nt = 0; nt < 3; ++nt) {
            short8 bb = *(const short8*)&U.bs[(nt * 16 + col) * 776 + k0 + quad * 8];
            acc[0][nt] = __builtin_amdgcn_mfma_f32_16x16x32_bf16(a[0], bb, acc[0][nt], 0, 0, 0);
            acc[1][nt] = __builtin_amdgcn_mfma_f32_16x16x32_bf16(a[1], bb, acc[1][nt], 0, 0, 0);
        }
    }

    __syncthreads();
#pragma unroll
    for (int mt = 0; mt < 2; ++mt)
#pragma unroll
        for (int nt = 0; nt < 3; ++nt)
#pragma unroll
            for (int rr = 0; rr < 4; ++rr) {
                int lrow = wv * 32 + mt * 16 + quad * 4 + rr;
                int c = nt * 16 + col;
                U.ep.pre[lrow * 52 + c] = acc[mt][nt][rr] + biasL[c];
            }
    __syncthreads();
    for (int i = tid; i < 3072; i += 256) {
        int t = i / 24, c = i - t * 24;
        U.ep.h[t * 28 + c] = sigf(U.ep.pre[t * 52 + c]) * tanhfast(U.ep.pre[t * 52 + 24 + c]);
    }
    __syncthreads();
    {
        int t = tid >> 1, half = tid & 1;
        float hv[24];
#pragma unroll
        for (int q = 0; q < 6; ++q) {
            float4 v = *(const float4*)&U.ep.h[t * 28 + q * 4];
            hv[q * 4] = v.x; hv[q * 4 + 1] = v.y; hv[q * 4 + 2] = v.z; hv[q * 4 + 3] = v.w;
        }
        if (m0 + t < L) {
#pragma unroll
            for (int j = 0; j < 12; ++j) {
                int n = half * 12 + j;
                float o = sbL[n];
#pragma unroll
                for (int q = 0; q < 6; ++q) {
                    float4 w = *(const float4*)&WsT[n * 28 + q * 4];
                    o += hv[q*4] * w.x + hv[q*4+1] * w.y + hv[q*4+2] * w.z + hv[q*4+3] * w.w;
                }
                P[(long)b * PBSTR + (long)(m0 + t) * 24 + n] = o;
            }
        }
    }
}

// ---------------------------------------------------------------------------
__global__ __launch_bounds__(256) void gated_layer(
    const float* __restrict__ P,
    const float* __restrict__ gW, const float* __restrict__ gb,
    const float* __restrict__ fW, const float* __restrict__ fb,
    const float* __restrict__ sW, const float* __restrict__ sb,
    float* __restrict__ Q, int Lin, int Lout, int d, int trimOff)
{
    __shared__ float WgT[24 * 48];
    __shared__ float WfT[24 * 48];
    __shared__ float WsT[24 * 28];
    __shared__ float sCat[64 * 48];
    __shared__ float s2[64 * 28];
    __shared__ float hbuf[64 * 28];
    __shared__ float gbL[24], fbL[24], sbL[24];
    const int tid = threadIdx.x;
    const int m0 = blockIdx.x * 64;
    const int b = blockIdx.z;
    const float* Pb = P + (long)b * PBSTR;

    for (int i = tid; i < 1152; i += 256) {
        int tap = i / 576, r = i % 576, ci = r / 24, n = r % 24;
        WgT[n * 48 + tap * 24 + ci] = gW[i];
        WfT[n * 48 + tap * 24 + ci] = fW[i];
    }
    for (int i = tid; i < 576; i += 256) { int c = i / 24, n = i % 24; WsT[n * 28 + c] = sW[i]; }
    if (tid < 24) { gbL[tid] = gb[tid]; fbL[tid] = fb[tid]; sbL[tid] = sb[tid]; }
    for (int i = tid; i < 1536; i += 256) {
        int t = i / 24, c = i % 24;
        int r0 = m0 + t, r1 = r0 + d;
        sCat[t * 48 + c]      = (r0 < Lin) ? Pb[(long)r0 * 24 + c] : 0.f;
        sCat[t * 48 + 24 + c] = (r1 < Lin) ? Pb[(long)r1 * 24 + c] : 0.f;
        if (trimOff >= 0) {
            int r2 = r0 + trimOff;
            s2[t * 28 + c] = (r2 < Lin) ? Pb[(long)r2 * 24 + c] : 0.f;
        }
    }
    __syncthreads();
    if (tid < 192) {
        int c = tid % 24, tg = tid / 24;
        float ag[8], af[8];
#pragma unroll
        for (int tt = 0; tt < 8; ++tt) { ag[tt] = gbL[c]; af[tt] = fbL[c]; }
#pragma unroll
        for (int q = 0; q < 12; ++q) {
            float4 wg = *(const float4*)&WgT[c * 48 + q * 4];
            float4 wf = *(const float4*)&WfT[c * 48 + q * 4];
#pragma unroll
            for (int tt = 0; tt < 8; ++tt) {
                float4 sv = *(const float4*)&sCat[(tg * 8 + tt) * 48 + q * 4];
                ag[tt] += sv.x * wg.x + sv.y * wg.y + sv.z * wg.z + sv.w * wg.w;
                af[tt] += sv.x * wf.x + sv.y * wf.y + sv.z * wf.z + sv.w * wf.w;
            }
        }
#pragma unroll
        for (int tt = 0; tt < 8; ++tt)
            hbuf[(tg * 8 + tt) * 28 + c] = sigf(ag[tt]) * tanhfast(af[tt]);
    }
    __syncthreads();
    if (tid < 192) {
        int n = tid % 24, tg = tid / 24;
        float o[8];
#pragma unroll
        for (int tt = 0; tt < 8; ++tt) o[tt] = sbL[n];
#pragma unroll
        for (int q = 0; q < 6; ++q) {
            float4 w = *(const float4*)&WsT[n * 28 + q * 4];
#pragma unroll
            for (int tt = 0; tt < 8; ++tt) {
                float4 hv = *(const float4*)&hbuf[(tg * 8 + tt) * 28 + q * 4];
                o[tt] += hv.x * w.x + hv.y * w.y + hv.z * w.z + hv.w * w.w;
            }
        }
#pragma unroll
        for (int tt = 0; tt < 8; ++tt) {
            int t = m0 + tg * 8 + tt;
            if (t < Lout) {
                float v = o[tt];
                if (trimOff >= 0) v += s2[(tg * 8 + tt) * 28 + n];
                Q[(long)b * PBSTR + (long)t * 24 + n] = v;
            }
        }
    }
}

// ---------------------------------------------------------------------------
__global__ __launch_bounds__(256) void f2_softmax_v2(
    const u16* __restrict__ A, const u16* __restrict__ Wt2,
    const float* __restrict__ bias, float* __restrict__ out)
{
    __shared__ __align__(16) u16 Bs[2][256 * 40];
    __shared__ float biasL[256];
    const int tid = threadIdx.x;
    const int b = blockIdx.y;
    const int t0 = blockIdx.x * 64;
    biasL[tid] = bias[tid];

    const int wv = tid >> 6, lane = tid & 63, col = lane & 15, quad = lane >> 4;
    const u16* Ab = A + (long)b * (15360L * 256);
    const int row = t0 + wv * 16 + col;

    auto stage = [&](int kc, int buf) {
#pragma unroll
        for (int j = 0; j < 4; ++j) {
            int idx = tid * 4 + j;
            int rn = idx >> 2, kk = idx & 3;
            *(uint4*)&Bs[buf][rn * 40 + kk * 8] =
                *(const uint4*)(Wt2 + (long)rn * 256 + kc * 32 + kk * 8);
        }
    };

    short8 afr[8];
#pragma unroll
    for (int kc = 0; kc < 8; ++kc)
        afr[kc] = *(const short8*)(Ab + (long)row * 256 + kc * 32 + quad * 8);

    f32x4 acc[16];
#pragma unroll
    for (int i = 0; i < 16; ++i) acc[i] = (f32x4){0.f, 0.f, 0.f, 0.f};

    stage(0, 0);
    __syncthreads();
    for (int kc = 0; kc < 8; ++kc) {
        int buf = kc & 1;
        if (kc < 7) stage(kc + 1, buf ^ 1);
#pragma unroll
        for (int nt = 0; nt < 16; ++nt) {
            short8 bb = *(const short8*)&Bs[buf][(nt * 16 + col) * 40 + quad * 8];
            acc[nt] = __builtin_amdgcn_mfma_f32_16x16x32_bf16(afr[kc], bb, acc[nt], 0, 0, 0);
        }
        __syncthreads();
    }

#pragma unroll
    for (int r = 0; r < 4; ++r) {
        int tl = wv * 16 + quad * 4 + r;
        float v[16];
        float m = -1e30f;
#pragma unroll
        for (int nt = 0; nt < 16; ++nt) {
            v[nt] = acc[nt][r] + biasL[nt * 16 + col];
            m = fmaxf(m, v[nt]);
        }
        m = fmaxf(m, __shfl_xor(m, 1));
        m = fmaxf(m, __shfl_xor(m, 2));
        m = fmaxf(m, __shfl_xor(m, 4));
        m = fmaxf(m, __shfl_xor(m, 8));
        float s = 0.f;
#pragma unroll
        for (int nt = 0; nt < 16; ++nt) { v[nt] = __expf(v[nt] - m); s += v[nt]; }
        s += __shfl_xor(s, 1);
        s += __shfl_xor(s, 2);
        s += __shfl_xor(s, 4);
        s += __shfl_xor(s, 8);
        float inv = 1.f / s;
        float* op = out + ((long)b * 15360 + t0 + tl) * 256;
#pragma unroll
        for (int nt = 0; nt < 16; ++nt) op[nt * 16 + col] = v[nt] * inv;
    }
}

// ---------------------------------------------------------------------------
extern "C" void kernel_launch(void* const* d_in, const int* in_sizes, int n_in,
                              void* d_out, int out_size, void* d_ws, size_t ws_size,
                              hipStream_t stream)
{
    const float* x        = (const float*)d_in[0];
    const float* causal_W = (const float*)d_in[1];
    const float* causal_b = (const float*)d_in[2];
    const float* gW0      = (const float*)d_in[3];
    const float* gb0      = (const float*)d_in[4];
    const float* fW0      = (const float*)d_in[5];
    const float* fb0      = (const float*)d_in[6];
    const float* sW0      = (const float*)d_in[7];
    const float* sb0      = (const float*)d_in[8];
    const float* gate_W   = (const float*)d_in[9];
    const float* gate_b   = (const float*)d_in[10];
    const float* filter_W = (const float*)d_in[11];
    const float* filter_b = (const float*)d_in[12];
    const float* scale_W  = (const float*)d_in[13];
    const float* scale_b  = (const float*)d_in[14];
    const float* res_W    = (const float*)d_in[15];
    const float* res_b    = (const float*)d_in[16];
    const float* f1_W     = (const float*)d_in[17];
    const float* f1_b     = (const float*)d_in[18];
    const float* f2_W     = (const float*)d_in[19];
    const float* f2_b     = (const float*)d_in[20];

    char* w = (char*)d_ws;
    u16* ACC  = (u16*)w;   w += (size_t)8 * 15360 * 128 * 2;
    u16* A1   = (u16*)w;   w += (size_t)8 * 15360 * 256 * 2;
    float* P0 = (float*)w; w += (size_t)8 * 16382 * 24 * 4;
    float* P1 = (float*)w; w += (size_t)8 * 16382 * 24 * 4;
    u16* WtGF = (u16*)w;   w += (size_t)64 * 768 * 2;
    u16* Wt1  = (u16*)w;   w += (size_t)256 * 128 * 2;
    u16* Wt2  = (u16*)w;   w += (size_t)256 * 256 * 2;
    u16* Wtr  = (u16*)w;   w += (size_t)128 * 32 * 2;
    float* biasGF = (float*)w; w += 256;

    dim3 blk(256);

    build_gf_w<<<dim3(192), blk, 0, stream>>>(causal_W, causal_b, gW0, gb0, fW0, fb0,
                                              WtGF, biasGF);
    build_wt_misc<<<dim3(400), blk, 0, stream>>>(f1_W, f2_W, res_W + (size_t)8 * 24 * 128,
                                                 Wt1, Wt2, Wtr);

    gf_fused_v2<<<dim3(128, 1, 8), blk, 0, stream>>>(x, WtGF, biasGF, sW0, sb0, P0);

    float* Pprev = P0;
    float* Pnext = P1;
    int Lprev = 16382;
    for (int i = 0; i < 9; ++i) {
        int d = 2 << i;
        int L = Lprev - d;
        int trim = (i == 8) ? d / 2 : -1;
        gated_layer<<<dim3((L + 63) / 64, 1, 8), blk, 0, stream>>>(
            Pprev, gate_W + (size_t)i * 1152, gate_b + i * 24,
            filter_W + (size_t)i * 1152, filter_b + i * 24,
            scale_W + (size_t)i * 576, scale_b + i * 24,
            Pnext, Lprev, L, d, trim);
        float* tmp = Pprev; Pprev = Pnext; Pnext = tmp;
        Lprev = L;
    }

    gemm_bstat<float, 32, 8, 1><<<dim3(120, 1, 8), blk, 0, stream>>>(
        Pprev, PBSTR, 24, Wtr, 32, res_b + 8 * 128,
        ACC, (long)15360 * 128, 128, 15360);

    gemm_bstat<u16, 128, 8, 1><<<dim3(120, 2, 8), blk, 0, stream>>>(
        ACC, (long)15360 * 128, 128, Wt1, 128, f1_b,
        A1, (long)15360 * 256, 256, 15360);

    f2_softmax_v2<<<dim3(240, 8), blk, 0, stream>>>(A1, Wt2, f2_b, (float*)d_out);
}